// Round 13
// baseline (136.943 us; speedup 1.0000x reference)
//
#include <hip/hip_runtime.h>
#include <hip/hip_bf16.h>

typedef __attribute__((ext_vector_type(8))) __bf16 bf16x8;
typedef __attribute__((ext_vector_type(4))) __bf16 bf16x4;
typedef __attribute__((ext_vector_type(4))) float f32x4;
typedef __attribute__((ext_vector_type(16))) float f32x16;
typedef __attribute__((ext_vector_type(4))) unsigned u32x4;

#define DIM 2048
#define SEQ 2048
#define NH 32
#define NKV 8
#define HD 64
#define QKVD 3072          // 2048 Q | 512 K | 512 V packed columns
#define KOFF 2048
#define VOFF 2560
#define KVDIM 512

// async global->LDS, 16B per lane, wave-uniform LDS base (HW: base + lane*16)
__device__ __forceinline__ void gld16(const __bf16* g, __bf16* l) {
    __builtin_amdgcn_global_load_lds(
        (const __attribute__((address_space(1))) void*)g,
        (__attribute__((address_space(3))) void*)l, 16, 0, 0);
}

__device__ __forceinline__ unsigned cvtpk(float lo, float hi) {
    unsigned r;
    asm("v_cvt_pk_bf16_f32 %0, %1, %2" : "=v"(r) : "v"(lo), "v"(hi));
    return r;
}

// ---------------- fused fp32 -> bf16 convert, all 5 tensors ----------------
__global__ __launch_bounds__(256) void cvt_all(const float* __restrict__ x,
                                               const float* __restrict__ wq,
                                               const float* __restrict__ wk,
                                               const float* __restrict__ wv,
                                               const float* __restrict__ wo,
                                               __bf16* __restrict__ xb,
                                               __bf16* __restrict__ wqkvb,
                                               __bf16* __restrict__ wob) {
    const int i = blockIdx.x * blockDim.x + threadIdx.x;
    const int NX = SEQ * DIM / 4;          // 1048576
    const int NW = DIM * DIM / 4;          // 1048576
    const int NKV4 = KVDIM * DIM / 4;      // 262144
    const float* src; __bf16* dst; int off;
    if (i < NX)                        { src = x;  dst = xb;    off = i; }
    else if (i < NX + NW)              { src = wq; dst = wqkvb; off = i - NX; }
    else if (i < NX + NW + NKV4)       { src = wk; dst = wqkvb + (size_t)KOFF * DIM; off = i - NX - NW; }
    else if (i < NX + NW + 2 * NKV4)   { src = wv; dst = wqkvb + (size_t)VOFF * DIM; off = i - NX - NW - NKV4; }
    else                               { src = wo; dst = wob;   off = i - NX - NW - 2 * NKV4; }
    float4 v = reinterpret_cast<const float4*>(src)[off];
    bf16x4 o;
    o[0] = (__bf16)v.x; o[1] = (__bf16)v.y; o[2] = (__bf16)v.z; o[3] = (__bf16)v.w;
    reinterpret_cast<bf16x4*>(dst)[off] = o;
}

// ---------------- TN GEMM: 128x64 tile, 8 waves x (32x32), BK=64, dbuf ------
// (unchanged round-11 winner)
template <typename OutT, bool ROPE>
__global__ __launch_bounds__(512, 6) void gemm_tn(const __bf16* __restrict__ A,
                                                  const __bf16* __restrict__ B,
                                                  OutT* __restrict__ C,
                                                  int M, int N, int K,
                                                  float scale, int scaleNlim,
                                                  const float* __restrict__ fc,
                                                  const float* __restrict__ fs,
                                                  __bf16* __restrict__ VTout) {
    __shared__ __align__(16) __bf16 As[2][2][128 * 32];   // 32 KB
    __shared__ __align__(16) __bf16 Bs[2][2][64 * 32];    // 16 KB
    const int tid = threadIdx.x;
    const int lane = tid & 63;
    const int w = tid >> 6;               // 0..7
    const int l15 = lane & 15, lhi = lane >> 4;
    const int mb = blockIdx.y * 128;
    const int nb = blockIdx.x * 64;
    const int wm = (w >> 1) * 32, wn = (w & 1) * 32;

    const int srow = lane >> 2, scol = (lane & 3) * 8;
    const __bf16* gA = A + (size_t)(mb + w * 16 + srow) * K + scol;
    const __bf16* gB = B + (size_t)(nb + (w & 3) * 16 + srow) * K + scol;
    const int bsub = w >> 2;

    auto stage = [&](int kk, int buf) {
#pragma unroll
        for (int s = 0; s < 2; ++s)
            gld16(gA + kk + s * 32, As[buf][s] + w * 512);
        gld16(gB + kk + bsub * 32, Bs[buf][bsub] + (w & 3) * 512);
    };

    stage(0, 0);
    __syncthreads();

    f32x4 acc[2][2] = {};
    int cur = 0;
    for (int kk = 0; kk < K; kk += 64, cur ^= 1) {
        if (kk + 64 < K) stage(kk + 64, cur ^ 1);
#pragma unroll
        for (int s = 0; s < 2; ++s) {
            bf16x8 a[2], b[2];
#pragma unroll
            for (int i = 0; i < 2; ++i)
                a[i] = *reinterpret_cast<const bf16x8*>(&As[cur][s][(wm + i * 16 + l15) * 32 + lhi * 8]);
#pragma unroll
            for (int j = 0; j < 2; ++j)
                b[j] = *reinterpret_cast<const bf16x8*>(&Bs[cur][s][(wn + j * 16 + l15) * 32 + lhi * 8]);
#pragma unroll
            for (int i = 0; i < 2; ++i)
#pragma unroll
                for (int j = 0; j < 2; ++j)
                    acc[i][j] = __builtin_amdgcn_mfma_f32_16x16x32_bf16(a[i], b[j], acc[i][j], 0, 0, 0);
        }
        __syncthreads();
    }

    const bool toVT = ROPE && (VTout != nullptr) && (nb >= VOFF);
    if (toVT) {
#pragma unroll
        for (int i = 0; i < 2; ++i)
#pragma unroll
            for (int j = 0; j < 2; ++j) {
                bf16x4 pv;
#pragma unroll
                for (int r = 0; r < 4; ++r) pv[r] = (__bf16)acc[i][j][r];
                const int colv = nb - VOFF + wn + j * 16 + l15;
                const int row0 = mb + wm + i * 16 + lhi * 4;
                *reinterpret_cast<bf16x4*>(VTout + (size_t)colv * M + row0) = pv;
            }
    } else {
        const float sc = (nb < scaleNlim) ? scale : 1.0f;
        const bool doRope = ROPE && (nb < VOFF);
#pragma unroll
        for (int i = 0; i < 2; ++i)
#pragma unroll
            for (int j = 0; j < 2; ++j)
#pragma unroll
                for (int r = 0; r < 4; ++r) {
                    float v = acc[i][j][r] * sc;
                    if (doRope) {
                        const int col = nb + wn + j * 16 + l15;
                        const int row = mb + wm + i * 16 + lhi * 4 + r;
                        const float vp = __shfl_xor(v, 1);
                        const int fi = (col & 63) >> 1;
                        const float cc = fc[row * 32 + fi];
                        const float ss = fs[row * 32 + fi];
                        v = (col & 1) ? (vp * ss + v * cc) : (v * cc - vp * ss);
                    }
                    C[(size_t)(mb + wm + i * 16 + lhi * 4 + r) * N + nb + wn + j * 16 + l15] = (OutT)v;
                }
    }
}

// ---------------- Flash attention: 8-wave KV-shared, reg-P full-swap --------
// Grid 512 x 512thr: block = q-tiles {2p, 2p+1}; wave w -> qtl=w>>2,
// qhalf=w&1, kvhalf=(w>>1)&1. S^T AND O^T both have col=q=lane&31 ->
// softmax state fully lane-local; P goes sacc -> cvt_pk -> permlane32_swap
// -> PV B-operand (no LDS). K/V staged once per 64-kv tile for all 8 waves.
__global__ __launch_bounds__(512, 4) void attn_kernel(const __bf16* __restrict__ QKV,
                                                      const __bf16* __restrict__ VT,
                                                      __bf16* __restrict__ Y) {
    const int bx = blockIdx.x;
    const int g = bx >> 8;                 // 0/1
    const int a = (bx >> 5) & 7;
    const int h = bx & 31;
    const int p = g ? a : 15 - a;          // pair index; CU pair-sum = 34 iters
    const int kvh = h >> 2;
    const int tid = threadIdx.x;
    const int lane = tid & 63;
    const int w = tid >> 6;                // 0..7
    const int qtl = w >> 2, qhalf = w & 1, kvhalf = (w >> 1) & 1;
    const int l31 = lane & 31;
    const int lhi2 = lane >> 5;

    __shared__ __align__(16) __bf16 Kl[2][64 * 64];   // 16 KB, slot^(row&7) swz
    __shared__ __align__(16) __bf16 Vl[2][64 * 64];   // 16 KB, V^T, same swz
    __shared__ float ex[4][64][32];                   // 32 KB O-partial exchange
    __shared__ float exm[4][2][32];                   // 1 KB m/ls exchange

    const __bf16* Qp = QKV + h * HD;
    const __bf16* Kp = QKV + KOFF + kvh * HD;
    const __bf16* Vth = VT + (size_t)(kvh * HD) * SEQ;

    // staging: wave w stages K rows [8w,8w+8) and V^T rows [8w,8w+8)
    const int sr = lane >> 3;
    const int ksc = ((lane & 7) ^ sr) * 8;            // pre-swizzled src col

    auto stage = [&](int jt, int buf) {
        const int kvb = jt * 64;
        gld16(Kp + (size_t)(kvb + w * 8 + sr) * QKVD + ksc, &Kl[buf][w * 512]);
        gld16(Vth + (size_t)(w * 8 + sr) * SEQ + kvb + ksc, &Vl[buf][w * 512]);
    };

    const int qb = (2 * p + qtl) * 64 + qhalf * 32;   // wave's 32 q rows
    const int qrow = qb + l31;                        // lane's q column

    const __bf16* qptr = Qp + (size_t)qrow * QKVD;
    bf16x8 qf[4];
#pragma unroll
    for (int c = 0; c < 4; ++c)
        qf[c] = *reinterpret_cast<const bf16x8*>(qptr + c * 16 + lhi2 * 8);

    f32x16 o0 = {}, o1 = {};               // O^T partial, d-tiles 0/1, col=q
    float mrun = -1e30f;
    float lpart = 0.f;
    const int rsw7 = l31 & 7;

    const int nj = 2 * p + 2;
    stage(0, 0);
    __syncthreads();

    int cur = 0;
    for (int j = 0; j < nj; ++j, cur ^= 1) {
        if (j + 1 < nj) stage(j + 1, cur ^ 1);

        const int kvmin = j * 64 + kvhalf * 32;
        if (kvmin <= qb + 31) {            // not fully masked for this wave
            // ---- S^T(32kv x 32q): 4 MFMA over d
            f32x16 sacc = {};
            const __bf16* Kb = &Kl[cur][(kvhalf * 32 + l31) * 64];
            __builtin_amdgcn_s_setprio(1);
#pragma unroll
            for (int c = 0; c < 4; ++c) {
                bf16x8 kf = *reinterpret_cast<const bf16x8*>(
                    Kb + (((c * 2 + lhi2) ^ rsw7) * 8));
                sacc = __builtin_amdgcn_mfma_f32_32x32x16_bf16(kf, qf[c], sacc, 0, 0, 0);
            }
            __builtin_amdgcn_s_setprio(0);

            // ---- causal mask
            if (kvmin + 31 > qb) {
#pragma unroll
                for (int r = 0; r < 16; ++r) {
                    const int kv = kvmin + (r & 3) + 8 * (r >> 2) + 4 * lhi2;
                    if (kv > qrow) sacc[r] = -1e30f;
                }
            }

            // ---- lane-local online softmax (pair-uniform m via 1 shuffle)
            float pm = sacc[0];
#pragma unroll
            for (int r = 1; r < 16; ++r) pm = fmaxf(pm, sacc[r]);
            pm = fmaxf(pm, __shfl_xor(pm, 32));

            if (!__all(pm - mrun <= 8.0f)) {          // T13 defer-max
                const float mn = fmaxf(mrun, pm);
                const float aa = exp2f(mrun - mn);
                mrun = mn;
                lpart *= aa;
#pragma unroll
                for (int r = 0; r < 16; ++r) { o0[r] *= aa; o1[r] *= aa; }
            }

            // ---- P = exp2(S - m): pack pairs (lane-local)
            unsigned pk[4][2];
            float ps = 0.f;
#pragma unroll
            for (int g4 = 0; g4 < 4; ++g4) {
                float pv[4];
#pragma unroll
                for (int i = 0; i < 4; ++i) {
                    pv[i] = exp2f(sacc[g4 * 4 + i] - mrun);
                    ps += pv[i];
                }
                pk[g4][0] = cvtpk(pv[0], pv[1]);
                pk[g4][1] = cvtpk(pv[2], pv[3]);
            }
            lpart += ps;

            // ---- O^T += V^T . P : P fragment via permlane32_swap (T12)
            const __bf16* Vb0 = &Vl[cur][l31 * 64];
            const __bf16* Vb1 = &Vl[cur][(32 + l31) * 64];
            __builtin_amdgcn_s_setprio(1);
#pragma unroll
            for (int c = 0; c < 2; ++c) {
                auto sw0 = __builtin_amdgcn_permlane32_swap(pk[2 * c][0], pk[2 * c + 1][0], false, false);
                auto sw1 = __builtin_amdgcn_permlane32_swap(pk[2 * c][1], pk[2 * c + 1][1], false, false);
                u32x4 fw = {sw0[0], sw1[0], sw0[1], sw1[1]};
                bf16x8 pf = __builtin_bit_cast(bf16x8, fw);
                const int s = kvhalf * 4 + c * 2 + lhi2;
                bf16x8 vf0 = *reinterpret_cast<const bf16x8*>(Vb0 + ((s ^ rsw7) * 8));
                bf16x8 vf1 = *reinterpret_cast<const bf16x8*>(Vb1 + ((s ^ rsw7) * 8));
                o0 = __builtin_amdgcn_mfma_f32_32x32x16_bf16(vf0, pf, o0, 0, 0, 0);
                o1 = __builtin_amdgcn_mfma_f32_32x32x16_bf16(vf1, pf, o1, 0, 0, 0);
            }
            __builtin_amdgcn_s_setprio(0);
        }

        __syncthreads();   // drains gld16 prefetch + guards buffer reuse
    }

    // ---- epilogue: merge kv-half partials (flash merge), store ------------
    const float ls = lpart + __shfl_xor(lpart, 32);   // pair-combined row sum
    const int reg = qtl * 2 + qhalf;

    if (kvhalf) {
        float* dst = &ex[reg][lane][0];
#pragma unroll
        for (int r = 0; r < 16; ++r) { dst[r] = o0[r]; dst[16 + r] = o1[r]; }
        if (lane < 32) { exm[reg][0][l31] = mrun; exm[reg][1][l31] = ls; }
    }
    __syncthreads();
    if (!kvhalf) {
        const float mo = exm[reg][0][l31];
        const float lso = exm[reg][1][l31];
        const float mn = fmaxf(mrun, mo);
        const float A0 = exp2f(mrun - mn);
        const float A1 = exp2f(mo - mn);
        const float L = ls * A0 + lso * A1;
        const float* src = &ex[reg][lane][0];
        const size_t ybase = (size_t)qrow * DIM + h * HD;
#pragma unroll
        for (int g4 = 0; g4 < 4; ++g4) {
            bf16x4 y0, y1;
#pragma unroll
            for (int i = 0; i < 4; ++i) {
                const int r = g4 * 4 + i;
                y0[i] = (__bf16)((o0[r] * A0 + src[r] * A1) / L);
                y1[i] = (__bf16)((o1[r] * A0 + src[16 + r] * A1) / L);
            }
            const int d0 = 8 * g4 + 4 * lhi2;
            *reinterpret_cast<bf16x4*>(Y + ybase + d0) = y0;
            *reinterpret_cast<bf16x4*>(Y + ybase + 32 + d0) = y1;
        }
    }
}

extern "C" void kernel_launch(void* const* d_in, const int* in_sizes, int n_in,
                              void* d_out, int out_size, void* d_ws, size_t ws_size,
                              hipStream_t stream) {
    const float* x    = (const float*)d_in[0];
    const float* fcos = (const float*)d_in[1];
    const float* fsin = (const float*)d_in[2];
    const float* wq   = (const float*)d_in[3];
    const float* wk   = (const float*)d_in[4];
    const float* wv   = (const float*)d_in[5];
    const float* wo   = (const float*)d_in[6];
    float* out = (float*)d_out;

    __bf16* xb    = (__bf16*)d_ws;                       // [2048][2048]
    __bf16* wqkvb = xb + (size_t)SEQ * DIM;              // [3072][2048]
    __bf16* wob   = wqkvb + (size_t)QKVD * DIM;          // [2048][2048]
    __bf16* QKVb  = wob + (size_t)DIM * DIM;             // [2048][3072]
    __bf16* Yb    = QKVb + (size_t)SEQ * QKVD;           // [2048][2048]
    __bf16* VTb   = Yb + (size_t)SEQ * DIM;              // [512][2048]

    const int ncvt = (SEQ * DIM / 4) + 2 * (DIM * DIM / 4) + 2 * (KVDIM * DIM / 4);
    cvt_all<<<ncvt / 256, 256, 0, stream>>>(x, wq, wk, wv, wo, xb, wqkvb, wob);

    // fused QKV projection + RoPE + V-transpose; Q pre-scaled by 0.125*log2(e)
    gemm_tn<__bf16, true><<<dim3(QKVD / 64, SEQ / 128), 512, 0, stream>>>(
        xb, wqkvb, QKVb, SEQ, QKVD, DIM, 0.125f * 1.4426950408889634f, KOFF,
        fcos, fsin, VTb);

    attn_kernel<<<dim3(512), 512, 0, stream>>>(QKVb, VTb, Yb);

    gemm_tn<float, false><<<dim3(DIM / 64, SEQ / 128), 512, 0, stream>>>(
        Yb, wob, out, SEQ, DIM, DIM, 1.0f, 0, nullptr, nullptr, nullptr);
}